// Round 9
// baseline (417.562 us; speedup 1.0000x reference)
//
#include <hip/hip_runtime.h>
#include <stdint.h>

// out[b][o] = clamp((sum_k x[b][k]*W[o][k] + t[o]) >> (-n[o]), act_min[o], act_max[o])
// B=8192, IN=4096, OUT=4096. x,W arrive int32; harness reads d_out as int32.
//
// R9: flat GEMM, mfma_i32_32x32x32_i8. Block 128x128, 4 waves in 2x2 (wave tile
// 64x64 -> acc 64 AGPR), 2-deep register pipeline, 4 waves/SIMD occupancy,
// XCD-aware bn remap so each XCD's W slice (2 MB) is L2-resident. No barriers.

#define BDIM 8192
#define INDIM 4096
#define OUTDIM 4096

typedef __attribute__((ext_vector_type(4))) int I4;
typedef __attribute__((ext_vector_type(16))) int I16;

// ---------------- pack: int32 -> int8 in 32x32 fragment order ----------------
// row = tile*32 + (lane&31), k-bytes [(lane>>5)*16,+16) within 32B kb block.
// dst[((tile*128 + kb)*64 + lane)*16 + b]; tile stride = 1<<17 bytes.
__global__ __launch_bounds__(256) void pack_frag32(const int* __restrict__ x,
                                                   const int* __restrict__ W,
                                                   uint32_t* __restrict__ xp,
                                                   uint32_t* __restrict__ wp) {
    const uint32_t xq = (BDIM / 32) * 128 * 64;   // 2097152
    uint32_t u = blockIdx.x * 256 + threadIdx.x;
    const int* src;
    uint32_t* dst;
    if (u < xq) {
        uint32_t m32 = u >> 13, kb = (u >> 6) & 127, lane = u & 63;
        src = x + (size_t)(m32 * 32 + (lane & 31)) * INDIM + kb * 32 + (lane >> 5) * 16;
        dst = xp + (size_t)u * 4;
    } else {
        uint32_t v = u - xq;
        uint32_t n32 = v >> 13, kb = (v >> 6) & 127, lane = v & 63;
        src = W + (size_t)(n32 * 32 + (lane & 31)) * INDIM + kb * 32 + (lane >> 5) * 16;
        dst = wp + (size_t)v * 4;
    }
    uint32_t ow[4];
#pragma unroll
    for (int q = 0; q < 4; ++q) {
        int4 a = ((const int4*)src)[q];
        ow[q] = ((uint32_t)a.x & 255u)
              | (((uint32_t)a.y & 255u) << 8)
              | (((uint32_t)a.z & 255u) << 16)
              | (((uint32_t)a.w & 255u) << 24);
    }
    *(uint4*)dst = *(uint4*)ow;
}

#define LOAD_SET(fa, fb, off)                                            \
    do {                                                                 \
        _Pragma("unroll")                                                \
        for (int i = 0; i < 2; ++i) fa[i] = *(const I4*)(pa[i] + (off)); \
        _Pragma("unroll")                                                \
        for (int j = 0; j < 2; ++j) fb[j] = *(const I4*)(pb[j] + (off)); \
    } while (0)

#define MFMA_SET(fa, fb)                                                 \
    do {                                                                 \
        _Pragma("unroll")                                                \
        for (int i = 0; i < 2; ++i)                                      \
            _Pragma("unroll")                                            \
            for (int j = 0; j < 2; ++j)                                  \
                acc[i][j] = __builtin_amdgcn_mfma_i32_32x32x32_i8(fa[i], fb[j], acc[i][j], 0, 0, 0); \
    } while (0)

// ---------------- flat GEMM: block 128x128, 4 waves 2x2, wave 64x64 ----------------
__global__ __launch_bounds__(256, 4) void gemm_flat32(
    const uint8_t* __restrict__ Xp,   // fragment-ordered
    const uint8_t* __restrict__ Wp,   // fragment-ordered
    const int* __restrict__ t, const int* __restrict__ nsh,
    const int* __restrict__ amin, const int* __restrict__ amax,
    int* __restrict__ out) {

    // XCD-aware remap: XCD = blockIdx.x % 8 (grid.x=32, round-robin dispatch)
    // -> XCD k works bn in {4k..4k+3}: 2 MB of W, L2-resident.
    const int bn = (blockIdx.x & 7) * 4 + (blockIdx.x >> 3);  // 0..31 (OUT tiles of 128)
    const int bm = blockIdx.y;                                 // 0..63 (batch tiles of 128)
    const int tid = threadIdx.x;
    const int w = tid >> 6;               // 0..3
    const int lane = tid & 63;
    const int wr = w >> 1;                // row half (64)
    const int wc = w & 1;                 // col half (64)

    const uint8_t* pa[2];
    const uint8_t* pb[2];
#pragma unroll
    for (int i = 0; i < 2; ++i)
        pa[i] = Xp + ((size_t)(bm * 4 + wr * 2 + i) << 17) + lane * 16;
#pragma unroll
    for (int j = 0; j < 2; ++j)
        pb[j] = Wp + ((size_t)(bn * 4 + wc * 2 + j) << 17) + lane * 16;

    I16 acc[2][2];
#pragma unroll
    for (int i = 0; i < 2; ++i)
#pragma unroll
        for (int j = 0; j < 2; ++j)
#pragma unroll
            for (int r = 0; r < 16; ++r) acc[i][j][r] = 0;

    // 2-deep register pipeline over 128 K-sets (set stride = 1024 B)
    I4 a0[2], b0[2], a1[2], b1[2];
    LOAD_SET(a0, b0, 0);
    LOAD_SET(a1, b1, 1024);

#pragma unroll 1
    for (int kb = 0; kb < 125; kb += 2) {
        const size_t base = (size_t)kb * 1024;
        MFMA_SET(a0, b0);
        LOAD_SET(a0, b0, base + 2 * 1024);
        MFMA_SET(a1, b1);
        LOAD_SET(a1, b1, base + 3 * 1024);
    }
    // sets 126,127 already loaded
    MFMA_SET(a0, b0);
    MFMA_SET(a1, b1);

    // epilogue: 32x32 C/D layout col=lane&31, row=(reg&3)+8*(reg>>2)+4*(lane>>5)
#pragma unroll
    for (int j = 0; j < 2; ++j) {
        const int o = bn * 128 + wc * 64 + j * 32 + (lane & 31);
        const int tt = t[o];
        const int sh = -nsh[o];
        const int mn = amin[o];
        const int mx = amax[o];
#pragma unroll
        for (int i = 0; i < 2; ++i) {
            const int rowbase = bm * 128 + wr * 64 + i * 32 + 4 * (lane >> 5);
#pragma unroll
            for (int r = 0; r < 16; ++r) {
                const int row = rowbase + (r & 3) + 8 * (r >> 2);
                int v = acc[i][j][r] + tt;
                v >>= sh;
                v = v < mn ? mn : (v > mx ? mx : v);
                __builtin_nontemporal_store(v, &out[(size_t)row * OUTDIM + o]);
            }
        }
    }
}

extern "C" void kernel_launch(void* const* d_in, const int* in_sizes, int n_in,
                              void* d_out, int out_size, void* d_ws, size_t ws_size,
                              hipStream_t stream) {
    const int* x = (const int*)d_in[0];
    const int* W = (const int*)d_in[1];
    const int* t = (const int*)d_in[2];
    const int* n = (const int*)d_in[3];
    const int* amin = (const int*)d_in[4];
    const int* amax = (const int*)d_in[5];
    int* out = (int*)d_out;

    uint8_t* xp = (uint8_t*)d_ws;                    // 33554432 B (fragment order)
    uint8_t* wp = xp + (size_t)BDIM * INDIM;         // 16777216 B (fragment order)

    {
        int nthreads = (BDIM / 32) * 128 * 64 + (OUTDIM / 32) * 128 * 64;  // 3145728
        pack_frag32<<<nthreads / 256, 256, 0, stream>>>(x, W, (uint32_t*)xp, (uint32_t*)wp);
    }

    dim3 grid(OUTDIM / 128, BDIM / 128);  // (32 bn fast, 64 bm)
    gemm_flat32<<<grid, 256, 0, stream>>>(xp, wp, t, n, amin, amax, out);
}

// Round 10
// 394.280 us; speedup vs baseline: 1.0591x; 1.0591x over previous
//
#include <hip/hip_runtime.h>
#include <stdint.h>

// out[b][o] = clamp((sum_k x[b][k]*W[o][k] + t[o]) >> (-n[o]), act_min[o], act_max[o])
// B=8192, IN=4096, OUT=4096. x,W arrive int32; harness reads d_out as int32.
//
// R10: flat GEMM, mfma_i32_32x32x32_i8, ONE wave per block (64 threads), wave
// tile 128x128 (4x4 grid, acc=256 AGPR) -> fragment intensity 128 ops/byte.
// 3-deep register pipeline (~1170 cyc prefetch distance) hides latency in-wave.
// 2048 blocks = 2 full rounds at 4 blocks/CU (1 wave/SIMD).

#define BDIM 8192
#define INDIM 4096
#define OUTDIM 4096

typedef __attribute__((ext_vector_type(4))) int I4;
typedef __attribute__((ext_vector_type(16))) int I16;

// ---------------- pack: int32 -> int8 in 32x32 fragment order ----------------
// row = tile*32 + (lane&31), k-bytes [(lane>>5)*16,+16) within 32B kb block.
// dst[((tile*128 + kb)*64 + lane)*16 + b]; tile stride = 1<<17 bytes.
__global__ __launch_bounds__(256) void pack_frag32(const int* __restrict__ x,
                                                   const int* __restrict__ W,
                                                   uint32_t* __restrict__ xp,
                                                   uint32_t* __restrict__ wp) {
    const uint32_t xq = (BDIM / 32) * 128 * 64;   // 2097152
    uint32_t u = blockIdx.x * 256 + threadIdx.x;
    const int* src;
    uint32_t* dst;
    if (u < xq) {
        uint32_t m32 = u >> 13, kb = (u >> 6) & 127, lane = u & 63;
        src = x + (size_t)(m32 * 32 + (lane & 31)) * INDIM + kb * 32 + (lane >> 5) * 16;
        dst = xp + (size_t)u * 4;
    } else {
        uint32_t v = u - xq;
        uint32_t n32 = v >> 13, kb = (v >> 6) & 127, lane = v & 63;
        src = W + (size_t)(n32 * 32 + (lane & 31)) * INDIM + kb * 32 + (lane >> 5) * 16;
        dst = wp + (size_t)v * 4;
    }
    uint32_t ow[4];
#pragma unroll
    for (int q = 0; q < 4; ++q) {
        int4 a = ((const int4*)src)[q];
        ow[q] = ((uint32_t)a.x & 255u)
              | (((uint32_t)a.y & 255u) << 8)
              | (((uint32_t)a.z & 255u) << 16)
              | (((uint32_t)a.w & 255u) << 24);
    }
    *(uint4*)dst = *(uint4*)ow;
}

#define LOAD_SET(fa, fb, off)                                            \
    do {                                                                 \
        _Pragma("unroll")                                                \
        for (int i = 0; i < 4; ++i) fa[i] = *(const I4*)(pa[i] + (off)); \
        _Pragma("unroll")                                                \
        for (int j = 0; j < 4; ++j) fb[j] = *(const I4*)(pb[j] + (off)); \
    } while (0)

#define MFMA_SET(fa, fb)                                                 \
    do {                                                                 \
        _Pragma("unroll")                                                \
        for (int i = 0; i < 4; ++i)                                      \
            _Pragma("unroll")                                            \
            for (int j = 0; j < 4; ++j)                                  \
                acc[i][j] = __builtin_amdgcn_mfma_i32_32x32x32_i8(fa[i], fb[j], acc[i][j], 0, 0, 0); \
    } while (0)

// ---------------- flat GEMM: 1 wave/block, wave tile 128x128 ----------------
__global__ __launch_bounds__(64, 1) void gemm_flat32(
    const uint8_t* __restrict__ Xp,   // fragment-ordered
    const uint8_t* __restrict__ Wp,   // fragment-ordered
    const int* __restrict__ t, const int* __restrict__ nsh,
    const int* __restrict__ amin, const int* __restrict__ amax,
    int* __restrict__ out) {

    const int bn = blockIdx.x;            // 0..31 (OUT tiles of 128) — fast axis
    const int bm = blockIdx.y;            // 0..63 (batch tiles of 128)
    const int lane = threadIdx.x;         // 0..63 (one wave)

    const uint8_t* pa[4];
    const uint8_t* pb[4];
#pragma unroll
    for (int i = 0; i < 4; ++i)
        pa[i] = Xp + ((size_t)(bm * 4 + i) << 17) + lane * 16;
#pragma unroll
    for (int j = 0; j < 4; ++j)
        pb[j] = Wp + ((size_t)(bn * 4 + j) << 17) + lane * 16;

    I16 acc[4][4];
#pragma unroll
    for (int i = 0; i < 4; ++i)
#pragma unroll
        for (int j = 0; j < 4; ++j)
#pragma unroll
            for (int r = 0; r < 16; ++r) acc[i][j][r] = 0;

    // 3-deep register pipeline over 128 K-sets (set stride = 1024 B)
    I4 a0[4], b0[4], a1[4], b1[4], a2[4], b2[4];
    LOAD_SET(a0, b0, 0);
    LOAD_SET(a1, b1, 1024);
    LOAD_SET(a2, b2, 2048);

#pragma unroll 1
    for (int kb = 0; kb < 123; kb += 3) {
        const size_t base = (size_t)kb * 1024;
        MFMA_SET(a0, b0);
        LOAD_SET(a0, b0, base + 3 * 1024);
        MFMA_SET(a1, b1);
        LOAD_SET(a1, b1, base + 4 * 1024);
        MFMA_SET(a2, b2);
        LOAD_SET(a2, b2, base + 5 * 1024);
    }
    // after loop: a0=set123, a1=set124, a2=set125
    MFMA_SET(a0, b0);
    LOAD_SET(a0, b0, (size_t)126 * 1024);
    MFMA_SET(a1, b1);
    LOAD_SET(a1, b1, (size_t)127 * 1024);
    MFMA_SET(a2, b2);   // set 125
    MFMA_SET(a0, b0);   // set 126
    MFMA_SET(a1, b1);   // set 127

    // epilogue: 32x32 C/D layout col=lane&31, row=(reg&3)+8*(reg>>2)+4*(lane>>5)
#pragma unroll
    for (int j = 0; j < 4; ++j) {
        const int o = bn * 128 + j * 32 + (lane & 31);
        const int tt = t[o];
        const int sh = -nsh[o];
        const int mn = amin[o];
        const int mx = amax[o];
#pragma unroll
        for (int i = 0; i < 4; ++i) {
            const int rowbase = bm * 128 + i * 32 + 4 * (lane >> 5);
#pragma unroll
            for (int r = 0; r < 16; ++r) {
                const int row = rowbase + (r & 3) + 8 * (r >> 2);
                int v = acc[i][j][r] + tt;
                v >>= sh;
                v = v < mn ? mn : (v > mx ? mx : v);
                __builtin_nontemporal_store(v, &out[(size_t)row * OUTDIM + o]);
            }
        }
    }
}

extern "C" void kernel_launch(void* const* d_in, const int* in_sizes, int n_in,
                              void* d_out, int out_size, void* d_ws, size_t ws_size,
                              hipStream_t stream) {
    const int* x = (const int*)d_in[0];
    const int* W = (const int*)d_in[1];
    const int* t = (const int*)d_in[2];
    const int* n = (const int*)d_in[3];
    const int* amin = (const int*)d_in[4];
    const int* amax = (const int*)d_in[5];
    int* out = (int*)d_out;

    uint8_t* xp = (uint8_t*)d_ws;                    // 33554432 B (fragment order)
    uint8_t* wp = xp + (size_t)BDIM * INDIM;         // 16777216 B (fragment order)

    {
        int nthreads = (BDIM / 32) * 128 * 64 + (OUTDIM / 32) * 128 * 64;  // 3145728
        pack_frag32<<<nthreads / 256, 256, 0, stream>>>(x, W, (uint32_t*)xp, (uint32_t*)wp);
    }

    dim3 grid(OUTDIM / 128, BDIM / 128);  // (32 bn fast, 64 bm) = 2048 one-wave blocks
    gemm_flat32<<<grid, 64, 0, stream>>>(xp, wp, t, n, amin, amax, out);
}